// Round 2
// baseline (3113.732 us; speedup 1.0000x reference)
//
#include <hip/hip_runtime.h>
#include <cstdint>
#include <cstddef>

#define NN 100000
#define NE 1600000

// ---------------- graph preprocessing ----------------

static __global__ void k_init_deg(int* __restrict__ deg) {
    int i = blockIdx.x * 256 + threadIdx.x;
    if (i < NN) deg[i] = 1;  // self loop
}

static __global__ void k_count(const int* __restrict__ dst, int* __restrict__ deg) {
    int e = blockIdx.x * 256 + threadIdx.x;
    if (e < NE) atomicAdd(&deg[dst[e]], 1);
}

static __global__ void k_dinv(const int* __restrict__ deg, float* __restrict__ dinv) {
    int i = blockIdx.x * 256 + threadIdx.x;
    if (i < NN) dinv[i] = rsqrtf((float)deg[i]);  // deg >= 1 always
}

// exclusive scan of (deg[i]-1) -> row_ptr, chunk=1024/block
static __global__ void k_scan1(const int* __restrict__ deg, int* __restrict__ row_ptr,
                               int* __restrict__ bsums) {
    __shared__ int sd[256];
    int t = threadIdx.x;
    int base = blockIdx.x * 1024;
    int v[4];
    int s = 0;
#pragma unroll
    for (int j = 0; j < 4; j++) {
        int i = base + t * 4 + j;
        int c = (i < NN) ? (deg[i] - 1) : 0;
        v[j] = s;
        s += c;
    }
    sd[t] = s;
    __syncthreads();
    for (int off = 1; off < 256; off <<= 1) {
        int x = (t >= off) ? sd[t - off] : 0;
        __syncthreads();
        sd[t] += x;
        __syncthreads();
    }
    int excl = (t > 0) ? sd[t - 1] : 0;
#pragma unroll
    for (int j = 0; j < 4; j++) {
        int i = base + t * 4 + j;
        if (i < NN) row_ptr[i] = excl + v[j];
    }
    if (t == 255) bsums[blockIdx.x] = sd[255];
}

static __global__ void k_scan2(int* __restrict__ bsums, int nb) {
    if (blockIdx.x == 0 && threadIdx.x == 0) {
        int s = 0;
        for (int i = 0; i < nb; i++) {
            int c = bsums[i];
            bsums[i] = s;
            s += c;
        }
    }
}

static __global__ void k_scan3(int* __restrict__ row_ptr, int* __restrict__ cursor,
                               const int* __restrict__ bsums) {
    int i = blockIdx.x * 256 + threadIdx.x;
    if (i < NN) {
        int v = row_ptr[i] + bsums[i >> 10];
        row_ptr[i] = v;
        cursor[i] = v;
    } else if (i == NN) {
        row_ptr[NN] = NE;
    }
}

static __global__ void k_fill(const int* __restrict__ src, const int* __restrict__ dst,
                              int* __restrict__ cursor, int* __restrict__ csr_src) {
    int e = blockIdx.x * 256 + threadIdx.x;
    if (e < NE) {
        int d = dst[e];
        int pos = atomicAdd(&cursor[d], 1);
        csr_src[pos] = src[e];
    }
}

// ---------------- dense GEMM ----------------
// C[N, DOUT] = epilogue( A[N, DIN] @ W )
// TRANSB: W is [DOUT, DIN] accessed as W^T.
// RESID:  v = relu(A[row,col] + acc)   (needs DIN==DOUT)
// BIAS:   v = relu(acc + bias[col])
// SCALE:  v *= dinv[row]  (applied last, after relu)
template <int DIN, int DOUT, bool TRANSB, bool RESID, bool BIAS, bool SCALE>
__global__ __launch_bounds__(512, 4) void k_gemm(const float* __restrict__ A,
                                                 const float* __restrict__ W,
                                                 const float* __restrict__ bias,
                                                 const float* __restrict__ dinv,
                                                 float* __restrict__ C) {
    static_assert(!RESID || DIN == DOUT, "residual needs square");
    constexpr int COLS = DOUT / 32;  // 4 for 128, 2 for 64
    constexpr int LDW = DIN + 4;     // padded leading dim for transposed layout
    __shared__ float Ws[TRANSB ? (DOUT * LDW) : (DIN * DOUT)];
    const int t = threadIdx.x;

    if constexpr (!TRANSB) {
        const float4* Wv = (const float4*)W;
        float4* Sv = (float4*)Ws;
        for (int i = t; i < DIN * DOUT / 4; i += 512) Sv[i] = Wv[i];
    } else {
        constexpr int K4 = DIN / 4;
        for (int i = t; i < DOUT * K4; i += 512) {
            int j = i / K4, k4 = i - j * K4;
            float4 v = ((const float4*)W)[i];
            *(float4*)&Ws[j * LDW + 4 * k4] = v;
        }
    }
    __syncthreads();

    const int cg = t & 31;
    const int rg = t >> 5;                   // 0..15
    const int n0 = blockIdx.x * 64 + rg * 4; // 4 rows per thread

    float acc[4][COLS];
#pragma unroll
    for (int r = 0; r < 4; r++)
#pragma unroll
        for (int c = 0; c < COLS; c++) acc[r][c] = 0.f;

    const float* Arow[4];
#pragma unroll
    for (int r = 0; r < 4; r++) {
        int ri = min(n0 + r, NN - 1);  // clamp tail; store guarded
        Arow[r] = A + (size_t)ri * DIN;
    }

    float4 a_cur[4];
#pragma unroll
    for (int r = 0; r < 4; r++) a_cur[r] = *(const float4*)(Arow[r]);

    for (int k = 0; k < DIN; k += 4) {
        float4 a_nxt[4];
        if (k + 4 < DIN) {
#pragma unroll
            for (int r = 0; r < 4; r++) a_nxt[r] = *(const float4*)(Arow[r] + k + 4);
        }
        float w[4][COLS];
        if constexpr (!TRANSB) {
#pragma unroll
            for (int kk = 0; kk < 4; kk++) {
                if constexpr (COLS == 4) {
                    float4 wv = *(const float4*)&Ws[(k + kk) * DOUT + 4 * cg];
                    w[kk][0] = wv.x; w[kk][1] = wv.y; w[kk][2] = wv.z; w[kk][3] = wv.w;
                } else {
                    float2 wv = *(const float2*)&Ws[(k + kk) * DOUT + 2 * cg];
                    w[kk][0] = wv.x; w[kk][1] = wv.y;
                }
            }
        } else {
#pragma unroll
            for (int c = 0; c < COLS; c++) {
                float4 wv = *(const float4*)&Ws[(cg + 32 * c) * LDW + k];
                w[0][c] = wv.x; w[1][c] = wv.y; w[2][c] = wv.z; w[3][c] = wv.w;
            }
        }
#pragma unroll
        for (int r = 0; r < 4; r++) {
#pragma unroll
            for (int c = 0; c < COLS; c++)
                acc[r][c] = fmaf(a_cur[r].x, w[0][c],
                            fmaf(a_cur[r].y, w[1][c],
                            fmaf(a_cur[r].z, w[2][c],
                            fmaf(a_cur[r].w, w[3][c], acc[r][c]))));
        }
        if (k + 4 < DIN) {
#pragma unroll
            for (int r = 0; r < 4; r++) a_cur[r] = a_nxt[r];
        }
    }

#pragma unroll
    for (int r = 0; r < 4; r++) {
        int row = n0 + r;
        if (row < NN) {
            float scale = SCALE ? dinv[row] : 1.f;
#pragma unroll
            for (int c = 0; c < COLS; c++) {
                int col = TRANSB ? (cg + 32 * c) : (COLS * cg + c);
                float v = acc[r][c];
                if constexpr (RESID) v = fmaxf(v + A[(size_t)row * DIN + col], 0.f);
                if constexpr (BIAS)  v = fmaxf(v + bias[col], 0.f);
                if constexpr (SCALE) v *= scale;
                C[(size_t)row * DOUT + col] = v;
            }
        }
    }
}

// ---------------- GCN aggregation ----------------
// Input hs is PRE-SCALED: hs[i] = dinv[i] * h[i]  (done in producer GEMM epilogue).
// acc = hs[node] + sum_e hs[src_e]
// BIAS_RELU: out = relu(dinv[node]*acc + b)   else: out = dinv[node]*acc
template <int D, bool BIAS_RELU>
__global__ __launch_bounds__(256) void k_agg(const float* __restrict__ hs,
                                             const float* __restrict__ dinv,
                                             const int* __restrict__ row_ptr,
                                             const int* __restrict__ csr_src,
                                             const float* __restrict__ bias,
                                             float* __restrict__ out) {
    constexpr int V = D / 64;  // floats per lane: 2 (D=128) or 1 (D=64)
    int node = blockIdx.x * 4 + (threadIdx.x >> 6);
    int lane = threadIdx.x & 63;
    if (node >= NN) return;
    const int off = lane * V;

    float a0, a1 = 0.f;
    {
        const float* p = hs + (size_t)node * D + off;
        if constexpr (V == 2) { float2 v = *(const float2*)p; a0 = v.x; a1 = v.y; }
        else a0 = *p;
    }

    int e = row_ptr[node];
    const int end = row_ptr[node + 1];

    // 8-edge batches: 8 independent index loads + 8 independent row loads in flight
    for (; e + 8 <= end; e += 8) {
        int s[8];
#pragma unroll
        for (int i = 0; i < 8; i++) s[i] = csr_src[e + i];
        if constexpr (V == 2) {
            float2 v[8];
#pragma unroll
            for (int i = 0; i < 8; i++) v[i] = *(const float2*)(hs + (size_t)s[i] * D + off);
#pragma unroll
            for (int i = 0; i < 8; i++) { a0 += v[i].x; a1 += v[i].y; }
        } else {
            float v[8];
#pragma unroll
            for (int i = 0; i < 8; i++) v[i] = hs[(size_t)s[i] * D + off];
#pragma unroll
            for (int i = 0; i < 8; i++) a0 += v[i];
        }
    }
    for (; e + 4 <= end; e += 4) {
        int s[4];
#pragma unroll
        for (int i = 0; i < 4; i++) s[i] = csr_src[e + i];
        if constexpr (V == 2) {
            float2 v[4];
#pragma unroll
            for (int i = 0; i < 4; i++) v[i] = *(const float2*)(hs + (size_t)s[i] * D + off);
#pragma unroll
            for (int i = 0; i < 4; i++) { a0 += v[i].x; a1 += v[i].y; }
        } else {
            float v[4];
#pragma unroll
            for (int i = 0; i < 4; i++) v[i] = hs[(size_t)s[i] * D + off];
#pragma unroll
            for (int i = 0; i < 4; i++) a0 += v[i];
        }
    }
    for (; e < end; e++) {
        int s = csr_src[e];
        const float* p = hs + (size_t)s * D + off;
        if constexpr (V == 2) { float2 v = *(const float2*)p; a0 += v.x; a1 += v.y; }
        else a0 += *p;
    }

    const float di = dinv[node];
    a0 *= di;
    if constexpr (V == 2) a1 *= di;
    if constexpr (BIAS_RELU) {
        a0 = fmaxf(a0 + bias[off], 0.f);
        if constexpr (V == 2) a1 = fmaxf(a1 + bias[off + 1], 0.f);
    }
    float* po = out + (size_t)node * D + off;
    if constexpr (V == 2) { *(float2*)po = make_float2(a0, a1); }
    else *po = a0;
}

// ---------------- launch ----------------

extern "C" void kernel_launch(void* const* d_in, const int* in_sizes, int n_in,
                              void* d_out, int out_size, void* d_ws, size_t ws_size,
                              hipStream_t stream) {
    const float* x   = (const float*)d_in[0];
    const int*   ei  = (const int*)d_in[1];
    const float* g1w = (const float*)d_in[2];
    const float* g1b = (const float*)d_in[3];
    const float* f2w = (const float*)d_in[4];
    const float* g3w = (const float*)d_in[5];
    const float* g3b = (const float*)d_in[6];
    const float* f4w = (const float*)d_in[7];
    const float* g5w = (const float*)d_in[8];
    const float* g5b = (const float*)d_in[9];
    const float* f6w = (const float*)d_in[10];
    float* out = (float*)d_out;

    const int* src = ei;       // edge_index[0]
    const int* dst = ei + NE;  // edge_index[1]

    char* p = (char*)d_ws;
    auto alloc = [&](size_t bytes) -> void* {
        void* r = (void*)p;
        p += (bytes + 255) & ~(size_t)255;
        return r;
    };
    int*   deg     = (int*)alloc(NN * 4);
    float* dinv    = (float*)alloc(NN * 4);
    int*   row_ptr = (int*)alloc((NN + 1) * 4);
    int*   cursor  = (int*)alloc(NN * 4);
    int*   bsums   = (int*)alloc(512);
    int*   csr     = (int*)alloc(NE * 4);
    float* bufA    = (float*)alloc((size_t)NN * 128 * 4);
    float* bufB    = (float*)alloc((size_t)NN * 128 * 4);

    const int gN  = (NN + 255) / 256;
    const int gE  = (NE + 255) / 256;
    const int gS  = (NN + 1023) / 1024;     // 98
    const int gN1 = (NN + 1 + 255) / 256;
    const int gG  = (NN + 63) / 64;         // 1563 blocks x 512 threads
    const int gA  = NN / 4;                 // 25000

    // graph preprocessing
    k_init_deg<<<gN, 256, 0, stream>>>(deg);
    k_count<<<gE, 256, 0, stream>>>(dst, deg);
    k_dinv<<<gN, 256, 0, stream>>>(deg, dinv);
    k_scan1<<<gS, 256, 0, stream>>>(deg, row_ptr, bsums);
    k_scan2<<<1, 64, 0, stream>>>(bsums, gS);
    k_scan3<<<gN1, 256, 0, stream>>>(row_ptr, cursor, bsums);
    k_fill<<<gE, 256, 0, stream>>>(src, dst, cursor, csr);

    // layer 1: hs1 = dinv*(x@W1); z1 = relu(dinv*agg(hs1)+b1); z1' = relu(z1 + z1@fc2^T)
    k_gemm<128, 128, false, false, false, true><<<gG, 512, 0, stream>>>(x, g1w, nullptr, dinv, bufA);
    k_agg<128, true><<<gA, 256, 0, stream>>>(bufA, dinv, row_ptr, csr, g1b, bufB);
    k_gemm<128, 128, true, true, false, false><<<gG, 512, 0, stream>>>(bufB, f2w, nullptr, nullptr, bufA);

    // layer 2: hs2 = dinv*(z1'@W3); z2 = relu(dinv*agg(hs2)+b3); z2'' = dinv*relu(z2 + z2@fc4^T)
    k_gemm<128, 64, false, false, false, true><<<gG, 512, 0, stream>>>(bufA, g3w, nullptr, dinv, bufB);
    k_agg<64, true><<<gA, 256, 0, stream>>>(bufB, dinv, row_ptr, csr, g3b, bufA);
    k_gemm<64, 64, true, true, false, true><<<gG, 512, 0, stream>>>(bufA, f4w, nullptr, dinv, bufB);

    // layer 3 (reordered: aggregate at 64ch, then GEMM):
    // t3 = dinv*agg(z2''); z3 = relu(t3@W5 + b5); out = relu(z3 + z3@fc6^T)
    k_agg<64, false><<<gA, 256, 0, stream>>>(bufB, dinv, row_ptr, csr, nullptr, bufA);
    k_gemm<64, 128, false, false, true, false><<<gG, 512, 0, stream>>>(bufA, g5w, g5b, nullptr, bufB);
    k_gemm<128, 128, true, true, false, false><<<gG, 512, 0, stream>>>(bufB, f6w, nullptr, nullptr, out);
}

// Round 3
// 940.068 us; speedup vs baseline: 3.3122x; 3.3122x over previous
//
#include <hip/hip_runtime.h>
#include <cstdint>
#include <cstddef>

#define NN 100000
#define NE 1600000

// ---------------- graph preprocessing ----------------

static __global__ void k_init_deg(int* __restrict__ deg) {
    int i = blockIdx.x * 256 + threadIdx.x;
    if (i < NN) deg[i] = 1;  // self loop
}

static __global__ void k_count(const int* __restrict__ dst, int* __restrict__ deg) {
    int e = blockIdx.x * 256 + threadIdx.x;
    if (e < NE) atomicAdd(&deg[dst[e]], 1);
}

static __global__ void k_dinv(const int* __restrict__ deg, float* __restrict__ dinv) {
    int i = blockIdx.x * 256 + threadIdx.x;
    if (i < NN) dinv[i] = rsqrtf((float)deg[i]);  // deg >= 1 always
}

// exclusive scan of (deg[i]-1) -> row_ptr, chunk=1024/block
static __global__ void k_scan1(const int* __restrict__ deg, int* __restrict__ row_ptr,
                               int* __restrict__ bsums) {
    __shared__ int sd[256];
    int t = threadIdx.x;
    int base = blockIdx.x * 1024;
    int v[4];
    int s = 0;
#pragma unroll
    for (int j = 0; j < 4; j++) {
        int i = base + t * 4 + j;
        int c = (i < NN) ? (deg[i] - 1) : 0;
        v[j] = s;
        s += c;
    }
    sd[t] = s;
    __syncthreads();
    for (int off = 1; off < 256; off <<= 1) {
        int x = (t >= off) ? sd[t - off] : 0;
        __syncthreads();
        sd[t] += x;
        __syncthreads();
    }
    int excl = (t > 0) ? sd[t - 1] : 0;
#pragma unroll
    for (int j = 0; j < 4; j++) {
        int i = base + t * 4 + j;
        if (i < NN) row_ptr[i] = excl + v[j];
    }
    if (t == 255) bsums[blockIdx.x] = sd[255];
}

static __global__ void k_scan2(int* __restrict__ bsums, int nb) {
    if (blockIdx.x == 0 && threadIdx.x == 0) {
        int s = 0;
        for (int i = 0; i < nb; i++) {
            int c = bsums[i];
            bsums[i] = s;
            s += c;
        }
    }
}

static __global__ void k_scan3(int* __restrict__ row_ptr, int* __restrict__ cursor,
                               const int* __restrict__ bsums) {
    int i = blockIdx.x * 256 + threadIdx.x;
    if (i < NN) {
        int v = row_ptr[i] + bsums[i >> 10];
        row_ptr[i] = v;
        cursor[i] = v;
    } else if (i == NN) {
        row_ptr[NN] = NE;
    }
}

static __global__ void k_fill(const int* __restrict__ src, const int* __restrict__ dst,
                              int* __restrict__ cursor, int* __restrict__ csr_src) {
    int e = blockIdx.x * 256 + threadIdx.x;
    if (e < NE) {
        int d = dst[e];
        int pos = atomicAdd(&cursor[d], 1);
        csr_src[pos] = src[e];
    }
}

// ---------------- dense GEMM ----------------
// Round-1 structure: 256 threads, 8 rows/thread, __launch_bounds__(256,2).
// NOTE: (512,4) caps VGPRs at 128 -> scratch spill -> 33x write amplification
// (round-2 regression: VALUBusy 1.5%, WRITE_SIZE 1.7GB). Do not lower the cap.
// C[N, DOUT] = epilogue( A[N, DIN] @ W )
// TRANSB: W is [DOUT, DIN] accessed as W^T.
// RESID:  v = relu(A[row,col] + acc)   (needs DIN==DOUT)
// BIAS:   v = relu(acc + bias[col])
// SCALE:  v *= dinv[row]  (applied last, after relu)
template <int DIN, int DOUT, bool TRANSB, bool RESID, bool BIAS, bool SCALE>
__global__ __launch_bounds__(256, 2) void k_gemm(const float* __restrict__ A,
                                                 const float* __restrict__ W,
                                                 const float* __restrict__ bias,
                                                 const float* __restrict__ dinv,
                                                 float* __restrict__ C) {
    static_assert(!RESID || DIN == DOUT, "residual needs square");
    constexpr int COLS = DOUT / 32;  // 4 for 128, 2 for 64
    constexpr int LDW = DIN + 4;     // padded leading dim for transposed layout
    __shared__ float Ws[TRANSB ? (DOUT * LDW) : (DIN * DOUT)];
    const int t = threadIdx.x;

    if constexpr (!TRANSB) {
        const float4* Wv = (const float4*)W;
        float4* Sv = (float4*)Ws;
        for (int i = t; i < DIN * DOUT / 4; i += 256) Sv[i] = Wv[i];
    } else {
        constexpr int K4 = DIN / 4;
        for (int i = t; i < DOUT * K4; i += 256) {
            int j = i / K4, k4 = i - j * K4;
            float4 v = ((const float4*)W)[i];
            *(float4*)&Ws[j * LDW + 4 * k4] = v;
        }
    }
    __syncthreads();

    const int cg = t & 31;
    const int rg = t >> 5;                   // 0..7
    const int n0 = blockIdx.x * 64 + rg * 8; // 8 rows per thread

    float acc[8][COLS];
#pragma unroll
    for (int r = 0; r < 8; r++)
#pragma unroll
        for (int c = 0; c < COLS; c++) acc[r][c] = 0.f;

    int rowi[8];
#pragma unroll
    for (int r = 0; r < 8; r++) rowi[r] = min(n0 + r, NN - 1);  // clamp tail; store guarded

    for (int k = 0; k < DIN; k += 4) {
        float w[4][COLS];
        if constexpr (!TRANSB) {
#pragma unroll
            for (int kk = 0; kk < 4; kk++) {
                if constexpr (COLS == 4) {
                    float4 wv = *(const float4*)&Ws[(k + kk) * DOUT + 4 * cg];
                    w[kk][0] = wv.x; w[kk][1] = wv.y; w[kk][2] = wv.z; w[kk][3] = wv.w;
                } else {
                    float2 wv = *(const float2*)&Ws[(k + kk) * DOUT + 2 * cg];
                    w[kk][0] = wv.x; w[kk][1] = wv.y;
                }
            }
        } else {
#pragma unroll
            for (int c = 0; c < COLS; c++) {
                float4 wv = *(const float4*)&Ws[(cg + 32 * c) * LDW + k];
                w[0][c] = wv.x; w[1][c] = wv.y; w[2][c] = wv.z; w[3][c] = wv.w;
            }
        }
#pragma unroll
        for (int r = 0; r < 8; r++) {
            float4 a = *(const float4*)&A[(size_t)rowi[r] * DIN + k];
#pragma unroll
            for (int c = 0; c < COLS; c++)
                acc[r][c] = fmaf(a.x, w[0][c],
                            fmaf(a.y, w[1][c],
                            fmaf(a.z, w[2][c],
                            fmaf(a.w, w[3][c], acc[r][c]))));
        }
    }

#pragma unroll
    for (int r = 0; r < 8; r++) {
        int row = n0 + r;
        if (row < NN) {
            float scale = SCALE ? dinv[row] : 1.f;
#pragma unroll
            for (int c = 0; c < COLS; c++) {
                int col = TRANSB ? (cg + 32 * c) : (COLS * cg + c);
                float v = acc[r][c];
                if constexpr (RESID) v = fmaxf(v + A[(size_t)row * DIN + col], 0.f);
                if constexpr (BIAS)  v = fmaxf(v + bias[col], 0.f);
                if constexpr (SCALE) v *= scale;
                C[(size_t)row * DOUT + col] = v;
            }
        }
    }
}

// ---------------- GCN aggregation ----------------
// Input hs is PRE-SCALED: hs[i] = dinv[i] * h[i]  (done in producer GEMM epilogue).
// acc = hs[node] + sum_e hs[src_e]
// BIAS_RELU: out = relu(dinv[node]*acc + b)   else: out = dinv[node]*acc
template <int D, bool BIAS_RELU>
__global__ __launch_bounds__(256) void k_agg(const float* __restrict__ hs,
                                             const float* __restrict__ dinv,
                                             const int* __restrict__ row_ptr,
                                             const int* __restrict__ csr_src,
                                             const float* __restrict__ bias,
                                             float* __restrict__ out) {
    constexpr int V = D / 64;  // floats per lane: 2 (D=128) or 1 (D=64)
    int node = blockIdx.x * 4 + (threadIdx.x >> 6);
    int lane = threadIdx.x & 63;
    if (node >= NN) return;
    const int off = lane * V;

    float a0, a1 = 0.f;
    {
        const float* p = hs + (size_t)node * D + off;
        if constexpr (V == 2) { float2 v = *(const float2*)p; a0 = v.x; a1 = v.y; }
        else a0 = *p;
    }

    int e = row_ptr[node];
    const int end = row_ptr[node + 1];

    // 8-edge batches: 8 independent index loads + 8 independent row loads in flight
    for (; e + 8 <= end; e += 8) {
        int s[8];
#pragma unroll
        for (int i = 0; i < 8; i++) s[i] = csr_src[e + i];
        if constexpr (V == 2) {
            float2 v[8];
#pragma unroll
            for (int i = 0; i < 8; i++) v[i] = *(const float2*)(hs + (size_t)s[i] * D + off);
#pragma unroll
            for (int i = 0; i < 8; i++) { a0 += v[i].x; a1 += v[i].y; }
        } else {
            float v[8];
#pragma unroll
            for (int i = 0; i < 8; i++) v[i] = hs[(size_t)s[i] * D + off];
#pragma unroll
            for (int i = 0; i < 8; i++) a0 += v[i];
        }
    }
    for (; e + 4 <= end; e += 4) {
        int s[4];
#pragma unroll
        for (int i = 0; i < 4; i++) s[i] = csr_src[e + i];
        if constexpr (V == 2) {
            float2 v[4];
#pragma unroll
            for (int i = 0; i < 4; i++) v[i] = *(const float2*)(hs + (size_t)s[i] * D + off);
#pragma unroll
            for (int i = 0; i < 4; i++) { a0 += v[i].x; a1 += v[i].y; }
        } else {
            float v[4];
#pragma unroll
            for (int i = 0; i < 4; i++) v[i] = hs[(size_t)s[i] * D + off];
#pragma unroll
            for (int i = 0; i < 4; i++) a0 += v[i];
        }
    }
    for (; e < end; e++) {
        int s = csr_src[e];
        const float* p = hs + (size_t)s * D + off;
        if constexpr (V == 2) { float2 v = *(const float2*)p; a0 += v.x; a1 += v.y; }
        else a0 += *p;
    }

    const float di = dinv[node];
    a0 *= di;
    if constexpr (V == 2) a1 *= di;
    if constexpr (BIAS_RELU) {
        a0 = fmaxf(a0 + bias[off], 0.f);
        if constexpr (V == 2) a1 = fmaxf(a1 + bias[off + 1], 0.f);
    }
    float* po = out + (size_t)node * D + off;
    if constexpr (V == 2) { *(float2*)po = make_float2(a0, a1); }
    else *po = a0;
}

// ---------------- launch ----------------

extern "C" void kernel_launch(void* const* d_in, const int* in_sizes, int n_in,
                              void* d_out, int out_size, void* d_ws, size_t ws_size,
                              hipStream_t stream) {
    const float* x   = (const float*)d_in[0];
    const int*   ei  = (const int*)d_in[1];
    const float* g1w = (const float*)d_in[2];
    const float* g1b = (const float*)d_in[3];
    const float* f2w = (const float*)d_in[4];
    const float* g3w = (const float*)d_in[5];
    const float* g3b = (const float*)d_in[6];
    const float* f4w = (const float*)d_in[7];
    const float* g5w = (const float*)d_in[8];
    const float* g5b = (const float*)d_in[9];
    const float* f6w = (const float*)d_in[10];
    float* out = (float*)d_out;

    const int* src = ei;       // edge_index[0]
    const int* dst = ei + NE;  // edge_index[1]

    char* p = (char*)d_ws;
    auto alloc = [&](size_t bytes) -> void* {
        void* r = (void*)p;
        p += (bytes + 255) & ~(size_t)255;
        return r;
    };
    int*   deg     = (int*)alloc(NN * 4);
    float* dinv    = (float*)alloc(NN * 4);
    int*   row_ptr = (int*)alloc((NN + 1) * 4);
    int*   cursor  = (int*)alloc(NN * 4);
    int*   bsums   = (int*)alloc(512);
    int*   csr     = (int*)alloc(NE * 4);
    float* bufA    = (float*)alloc((size_t)NN * 128 * 4);
    float* bufB    = (float*)alloc((size_t)NN * 128 * 4);

    const int gN  = (NN + 255) / 256;
    const int gE  = (NE + 255) / 256;
    const int gS  = (NN + 1023) / 1024;     // 98
    const int gN1 = (NN + 1 + 255) / 256;
    const int gG  = (NN + 63) / 64;         // 1563 blocks x 256 threads
    const int gA  = NN / 4;                 // 25000

    // graph preprocessing
    k_init_deg<<<gN, 256, 0, stream>>>(deg);
    k_count<<<gE, 256, 0, stream>>>(dst, deg);
    k_dinv<<<gN, 256, 0, stream>>>(deg, dinv);
    k_scan1<<<gS, 256, 0, stream>>>(deg, row_ptr, bsums);
    k_scan2<<<1, 64, 0, stream>>>(bsums, gS);
    k_scan3<<<gN1, 256, 0, stream>>>(row_ptr, cursor, bsums);
    k_fill<<<gE, 256, 0, stream>>>(src, dst, cursor, csr);

    // layer 1: hs1 = dinv*(x@W1); z1 = relu(dinv*agg(hs1)+b1); z1' = relu(z1 + z1@fc2^T)
    k_gemm<128, 128, false, false, false, true><<<gG, 256, 0, stream>>>(x, g1w, nullptr, dinv, bufA);
    k_agg<128, true><<<gA, 256, 0, stream>>>(bufA, dinv, row_ptr, csr, g1b, bufB);
    k_gemm<128, 128, true, true, false, false><<<gG, 256, 0, stream>>>(bufB, f2w, nullptr, nullptr, bufA);

    // layer 2: hs2 = dinv*(z1'@W3); z2 = relu(dinv*agg(hs2)+b3); z2'' = dinv*relu(z2 + z2@fc4^T)
    k_gemm<128, 64, false, false, false, true><<<gG, 256, 0, stream>>>(bufA, g3w, nullptr, dinv, bufB);
    k_agg<64, true><<<gA, 256, 0, stream>>>(bufB, dinv, row_ptr, csr, g3b, bufA);
    k_gemm<64, 64, true, true, false, true><<<gG, 256, 0, stream>>>(bufA, f4w, nullptr, dinv, bufB);

    // layer 3 (reordered: aggregate at 64ch, then GEMM):
    // t3 = dinv*agg(z2''); z3 = relu(t3@W5 + b5); out = relu(z3 + z3@fc6^T)
    k_agg<64, false><<<gA, 256, 0, stream>>>(bufB, dinv, row_ptr, csr, nullptr, bufA);
    k_gemm<64, 128, false, false, true, false><<<gG, 256, 0, stream>>>(bufA, g5w, g5b, nullptr, bufB);
    k_gemm<128, 128, true, true, false, false><<<gG, 256, 0, stream>>>(bufB, f6w, nullptr, nullptr, out);
}

// Round 4
// 916.925 us; speedup vs baseline: 3.3958x; 1.0252x over previous
//
#include <hip/hip_runtime.h>
#include <cstdint>
#include <cstddef>

#define NN 100000
#define NE 1600000

typedef short short8 __attribute__((ext_vector_type(8)));
typedef float floatx4 __attribute__((ext_vector_type(4)));

// ---------------- graph preprocessing ----------------

static __global__ void k_init_deg(int* __restrict__ deg) {
    int i = blockIdx.x * 256 + threadIdx.x;
    if (i < NN) deg[i] = 1;  // self loop
}

static __global__ void k_count(const int* __restrict__ dst, int* __restrict__ deg) {
    int e = blockIdx.x * 256 + threadIdx.x;
    if (e < NE) atomicAdd(&deg[dst[e]], 1);
}

static __global__ void k_dinv(const int* __restrict__ deg, float* __restrict__ dinv) {
    int i = blockIdx.x * 256 + threadIdx.x;
    if (i < NN) dinv[i] = rsqrtf((float)deg[i]);  // deg >= 1 always
}

// exclusive scan of (deg[i]-1) -> row_ptr, chunk=1024/block
static __global__ void k_scan1(const int* __restrict__ deg, int* __restrict__ row_ptr,
                               int* __restrict__ bsums) {
    __shared__ int sd[256];
    int t = threadIdx.x;
    int base = blockIdx.x * 1024;
    int v[4];
    int s = 0;
#pragma unroll
    for (int j = 0; j < 4; j++) {
        int i = base + t * 4 + j;
        int c = (i < NN) ? (deg[i] - 1) : 0;
        v[j] = s;
        s += c;
    }
    sd[t] = s;
    __syncthreads();
    for (int off = 1; off < 256; off <<= 1) {
        int x = (t >= off) ? sd[t - off] : 0;
        __syncthreads();
        sd[t] += x;
        __syncthreads();
    }
    int excl = (t > 0) ? sd[t - 1] : 0;
#pragma unroll
    for (int j = 0; j < 4; j++) {
        int i = base + t * 4 + j;
        if (i < NN) row_ptr[i] = excl + v[j];
    }
    if (t == 255) bsums[blockIdx.x] = sd[255];
}

static __global__ void k_scan2(int* __restrict__ bsums, int nb) {
    if (blockIdx.x == 0 && threadIdx.x == 0) {
        int s = 0;
        for (int i = 0; i < nb; i++) {
            int c = bsums[i];
            bsums[i] = s;
            s += c;
        }
    }
}

static __global__ void k_scan3(int* __restrict__ row_ptr, int* __restrict__ cursor,
                               const int* __restrict__ bsums) {
    int i = blockIdx.x * 256 + threadIdx.x;
    if (i < NN) {
        int v = row_ptr[i] + bsums[i >> 10];
        row_ptr[i] = v;
        cursor[i] = v;
    } else if (i == NN) {
        row_ptr[NN] = NE;
    }
}

static __global__ void k_fill(const int* __restrict__ src, const int* __restrict__ dst,
                              int* __restrict__ cursor, int* __restrict__ csr_src) {
    int e = blockIdx.x * 256 + threadIdx.x;
    if (e < NE) {
        int d = dst[e];
        int pos = atomicAdd(&cursor[d], 1);
        csr_src[pos] = src[e];
    }
}

// ---------------- split-bf16 helper ----------------
// f = hi + lo + eps, eps ~ 2^-18 rel. RNE rounding to bf16.
__device__ __forceinline__ void split_bf16(float f, short& hi, short& lo) {
    union { float f; uint32_t u; } x;
    x.f = f;
    uint32_t uh = x.u + 0x7FFFu + ((x.u >> 16) & 1u);
    hi = (short)(uh >> 16);
    union { uint32_t u; float f; } hf;
    hf.u = (uh >> 16) << 16;
    float r = f - hf.f;
    union { float f; uint32_t u; } y;
    y.f = r;
    uint32_t ul = y.u + 0x7FFFu + ((y.u >> 16) & 1u);
    lo = (short)(ul >> 16);
}

// ---------------- MFMA GEMM (split-bf16, ~fp32 accuracy) ----------------
// C[N, DOUT] = epilogue( A[N, DIN] @ W ), A fp32 split to bf16 hi/lo, W split
// into LDS. 3 MFMAs per tile-kstep: hi*hi + hi*lo + lo*hi (lo*lo dropped).
// Block: 64 rows x DOUT cols; 4 waves x one 16-row M-tile; N in 64-col phases.
// MFMA layouts (m89/m91-verified):
//   A: lane holds A[m=lane&15][k=(lane>>4)*8+j], j=0..7
//   B: lane holds B[k=(lane>>4)*8+j][n=lane&15]
//   C/D: lane,reg -> row=(lane>>4)*4+reg, col=lane&15
template <int DIN, int DOUT, bool TRANSB, bool RESID, bool BIAS, bool SCALE>
__global__ __launch_bounds__(256, 2) void k_mgemm(const float* __restrict__ A,
                                                  const float* __restrict__ W,
                                                  const float* __restrict__ bias,
                                                  const float* __restrict__ dinv,
                                                  float* __restrict__ C) {
    static_assert(!RESID || DIN == DOUT, "residual needs square");
    constexpr int KSTEPS = DIN / 32;   // 4 or 2
    constexpr int NPH = DOUT / 64;     // 2 or 1
    constexpr int LDK = DIN + 8;       // shorts; n-stride = 2*LDK bytes, 16B-aligned
    __shared__ short lhi[64 * LDK];
    __shared__ short llo[64 * LDK];

    const int t = threadIdx.x;
    const int wave = t >> 6;
    const int lane = t & 63;
    const int r16 = lane & 15;
    const int kq = lane >> 4;

    const int m = blockIdx.x * 64 + wave * 16 + r16;
    const int mc = min(m, NN - 1);
    const float* Ap = A + (size_t)mc * DIN + kq * 8;

    // A fragments for all k-steps, held across phases
    short8 ah[KSTEPS], al[KSTEPS];
#pragma unroll
    for (int ks = 0; ks < KSTEPS; ks++) {
        float4 f0 = *(const float4*)(Ap + ks * 32);
        float4 f1 = *(const float4*)(Ap + ks * 32 + 4);
        float fe[8] = {f0.x, f0.y, f0.z, f0.w, f1.x, f1.y, f1.z, f1.w};
#pragma unroll
        for (int j = 0; j < 8; j++) {
            short h, l;
            split_bf16(fe[j], h, l);
            ah[ks][j] = h;
            al[ks][j] = l;
        }
    }

    floatx4 acc[NPH][4];
#pragma unroll
    for (int p = 0; p < NPH; p++)
#pragma unroll
        for (int q = 0; q < 4; q++) acc[p][q] = (floatx4){0.f, 0.f, 0.f, 0.f};

#pragma unroll 1
    for (int ph = 0; ph < NPH; ph++) {
        if (ph) __syncthreads();  // all reads of previous stage done
        // stage W^T rows [ph*64, ph*64+64) as bf16 hi/lo
        if constexpr (TRANSB) {
            // W is [DOUT][DIN] row-major: row n gives B[k][n]=W[n][k]
            const float2* W2 = (const float2*)(W + (size_t)ph * 64 * DIN);
            for (int i = t; i < 64 * DIN / 2; i += 256) {
                int n = i / (DIN / 2);
                int k2 = i - n * (DIN / 2);
                float2 v = W2[i];
                short h0, l0, h1, l1;
                split_bf16(v.x, h0, l0);
                split_bf16(v.y, h1, l1);
                int base = n * LDK + 2 * k2;
                lhi[base] = h0; lhi[base + 1] = h1;
                llo[base] = l0; llo[base + 1] = l1;
            }
        } else {
            // W is [DIN][DOUT]: B[k][n]=W[k][n]; transpose into LDS
            for (int i = t; i < 64 * DIN; i += 256) {
                int k = i >> 6;
                int nl = i & 63;
                float v = W[(size_t)k * DOUT + ph * 64 + nl];
                short h, l;
                split_bf16(v, h, l);
                lhi[nl * LDK + k] = h;
                llo[nl * LDK + k] = l;
            }
        }
        __syncthreads();

#pragma unroll
        for (int ks = 0; ks < KSTEPS; ks++) {
#pragma unroll
            for (int tile = 0; tile < 4; tile++) {
                const int off = (tile * 16 + r16) * LDK + ks * 32 + kq * 8;
                short8 bh = *(const short8*)&lhi[off];
                short8 bl = *(const short8*)&llo[off];
                acc[ph][tile] = __builtin_amdgcn_mfma_f32_16x16x32_bf16(ah[ks], bh, acc[ph][tile], 0, 0, 0);
                acc[ph][tile] = __builtin_amdgcn_mfma_f32_16x16x32_bf16(ah[ks], bl, acc[ph][tile], 0, 0, 0);
                acc[ph][tile] = __builtin_amdgcn_mfma_f32_16x16x32_bf16(al[ks], bh, acc[ph][tile], 0, 0, 0);
            }
        }
    }

    // epilogue
#pragma unroll
    for (int ph = 0; ph < NPH; ph++) {
#pragma unroll
        for (int tile = 0; tile < 4; tile++) {
            int col = ph * 64 + tile * 16 + r16;
#pragma unroll
            for (int r = 0; r < 4; r++) {
                int row = blockIdx.x * 64 + wave * 16 + kq * 4 + r;
                if (row < NN) {
                    float v = acc[ph][tile][r];
                    if constexpr (RESID) v = fmaxf(v + A[(size_t)row * DIN + col], 0.f);
                    if constexpr (BIAS)  v = fmaxf(v + bias[col], 0.f);
                    if constexpr (SCALE) v *= dinv[row];
                    C[(size_t)row * DOUT + col] = v;
                }
            }
        }
    }
}

// ---------------- GCN aggregation ----------------
// Input hs is PRE-SCALED: hs[i] = dinv[i] * h[i]  (producer GEMM epilogue).
// acc = hs[node] + sum_e hs[src_e]
// BIAS_RELU: out = relu(dinv[node]*acc + b)   else: out = dinv[node]*acc
template <int D, bool BIAS_RELU>
__global__ __launch_bounds__(256) void k_agg(const float* __restrict__ hs,
                                             const float* __restrict__ dinv,
                                             const int* __restrict__ row_ptr,
                                             const int* __restrict__ csr_src,
                                             const float* __restrict__ bias,
                                             float* __restrict__ out) {
    constexpr int V = D / 64;  // floats per lane: 2 (D=128) or 1 (D=64)
    int node = blockIdx.x * 4 + (threadIdx.x >> 6);
    int lane = threadIdx.x & 63;
    if (node >= NN) return;
    const int off = lane * V;

    float a0, a1 = 0.f;
    {
        const float* p = hs + (size_t)node * D + off;
        if constexpr (V == 2) { float2 v = *(const float2*)p; a0 = v.x; a1 = v.y; }
        else a0 = *p;
    }

    int e = row_ptr[node];
    const int end = row_ptr[node + 1];

    for (; e + 8 <= end; e += 8) {
        int s[8];
#pragma unroll
        for (int i = 0; i < 8; i++) s[i] = csr_src[e + i];
        if constexpr (V == 2) {
            float2 v[8];
#pragma unroll
            for (int i = 0; i < 8; i++) v[i] = *(const float2*)(hs + (size_t)s[i] * D + off);
#pragma unroll
            for (int i = 0; i < 8; i++) { a0 += v[i].x; a1 += v[i].y; }
        } else {
            float v[8];
#pragma unroll
            for (int i = 0; i < 8; i++) v[i] = hs[(size_t)s[i] * D + off];
#pragma unroll
            for (int i = 0; i < 8; i++) a0 += v[i];
        }
    }
    for (; e + 4 <= end; e += 4) {
        int s[4];
#pragma unroll
        for (int i = 0; i < 4; i++) s[i] = csr_src[e + i];
        if constexpr (V == 2) {
            float2 v[4];
#pragma unroll
            for (int i = 0; i < 4; i++) v[i] = *(const float2*)(hs + (size_t)s[i] * D + off);
#pragma unroll
            for (int i = 0; i < 4; i++) { a0 += v[i].x; a1 += v[i].y; }
        } else {
            float v[4];
#pragma unroll
            for (int i = 0; i < 4; i++) v[i] = hs[(size_t)s[i] * D + off];
#pragma unroll
            for (int i = 0; i < 4; i++) a0 += v[i];
        }
    }
    for (; e < end; e++) {
        int s = csr_src[e];
        const float* p = hs + (size_t)s * D + off;
        if constexpr (V == 2) { float2 v = *(const float2*)p; a0 += v.x; a1 += v.y; }
        else a0 += *p;
    }

    const float di = dinv[node];
    a0 *= di;
    if constexpr (V == 2) a1 *= di;
    if constexpr (BIAS_RELU) {
        a0 = fmaxf(a0 + bias[off], 0.f);
        if constexpr (V == 2) a1 = fmaxf(a1 + bias[off + 1], 0.f);
    }
    float* po = out + (size_t)node * D + off;
    if constexpr (V == 2) { *(float2*)po = make_float2(a0, a1); }
    else *po = a0;
}

// ---------------- launch ----------------

extern "C" void kernel_launch(void* const* d_in, const int* in_sizes, int n_in,
                              void* d_out, int out_size, void* d_ws, size_t ws_size,
                              hipStream_t stream) {
    const float* x   = (const float*)d_in[0];
    const int*   ei  = (const int*)d_in[1];
    const float* g1w = (const float*)d_in[2];
    const float* g1b = (const float*)d_in[3];
    const float* f2w = (const float*)d_in[4];
    const float* g3w = (const float*)d_in[5];
    const float* g3b = (const float*)d_in[6];
    const float* f4w = (const float*)d_in[7];
    const float* g5w = (const float*)d_in[8];
    const float* g5b = (const float*)d_in[9];
    const float* f6w = (const float*)d_in[10];
    float* out = (float*)d_out;

    const int* src = ei;       // edge_index[0]
    const int* dst = ei + NE;  // edge_index[1]

    char* p = (char*)d_ws;
    auto alloc = [&](size_t bytes) -> void* {
        void* r = (void*)p;
        p += (bytes + 255) & ~(size_t)255;
        return r;
    };
    int*   deg     = (int*)alloc(NN * 4);
    float* dinv    = (float*)alloc(NN * 4);
    int*   row_ptr = (int*)alloc((NN + 1) * 4);
    int*   cursor  = (int*)alloc(NN * 4);
    int*   bsums   = (int*)alloc(512);
    int*   csr     = (int*)alloc(NE * 4);
    float* bufA    = (float*)alloc((size_t)NN * 128 * 4);
    float* bufB    = (float*)alloc((size_t)NN * 128 * 4);

    const int gN  = (NN + 255) / 256;
    const int gE  = (NE + 255) / 256;
    const int gS  = (NN + 1023) / 1024;     // 98
    const int gN1 = (NN + 1 + 255) / 256;
    const int gG  = (NN + 63) / 64;         // 1563 blocks x 256 threads
    const int gA  = NN / 4;                 // 25000

    // graph preprocessing
    k_init_deg<<<gN, 256, 0, stream>>>(deg);
    k_count<<<gE, 256, 0, stream>>>(dst, deg);
    k_dinv<<<gN, 256, 0, stream>>>(deg, dinv);
    k_scan1<<<gS, 256, 0, stream>>>(deg, row_ptr, bsums);
    k_scan2<<<1, 64, 0, stream>>>(bsums, gS);
    k_scan3<<<gN1, 256, 0, stream>>>(row_ptr, cursor, bsums);
    k_fill<<<gE, 256, 0, stream>>>(src, dst, cursor, csr);

    // layer 1: hs1 = dinv*(x@W1); z1 = relu(dinv*agg(hs1)+b1); z1' = relu(z1 + z1@fc2^T)
    k_mgemm<128, 128, false, false, false, true><<<gG, 256, 0, stream>>>(x, g1w, nullptr, dinv, bufA);
    k_agg<128, true><<<gA, 256, 0, stream>>>(bufA, dinv, row_ptr, csr, g1b, bufB);
    k_mgemm<128, 128, true, true, false, false><<<gG, 256, 0, stream>>>(bufB, f2w, nullptr, nullptr, bufA);

    // layer 2: hs2 = dinv*(z1'@W3); z2 = relu(dinv*agg(hs2)+b3); z2'' = dinv*relu(z2 + z2@fc4^T)
    k_mgemm<128, 64, false, false, false, true><<<gG, 256, 0, stream>>>(bufA, g3w, nullptr, dinv, bufB);
    k_agg<64, true><<<gA, 256, 0, stream>>>(bufB, dinv, row_ptr, csr, g3b, bufA);
    k_mgemm<64, 64, true, true, false, true><<<gG, 256, 0, stream>>>(bufA, f4w, nullptr, dinv, bufB);

    // layer 3 (reordered: aggregate at 64ch, then GEMM):
    // t3 = dinv*agg(z2''); z3 = relu(t3@W5 + b5); out = relu(z3 + z3@fc6^T)
    k_agg<64, false><<<gA, 256, 0, stream>>>(bufB, dinv, row_ptr, csr, nullptr, bufA);
    k_mgemm<64, 128, false, false, true, false><<<gG, 256, 0, stream>>>(bufA, g5w, g5b, nullptr, bufB);
    k_mgemm<128, 128, true, true, false, false><<<gG, 256, 0, stream>>>(bufB, f6w, nullptr, nullptr, out);
}